// Round 16
// baseline (258.738 us; speedup 1.0000x reference)
//
#include <hip/hip_runtime.h>
#include <stdint.h>

// ---------------------------------------------------------------------------
// EncoderBlock: LN1 -> QKV GEMM -> MHA (flash) -> +resid -> LN2 -> FFN(GELU)
// bf16 MFMA (16x16x32), fp32 accumulate. S=4096, D=1024, H=8, hd=128, FF=4096.
// R16: QKV GEMM launch widened to 256 blocks — bid<192 = GEMM (unchanged),
//      bid>=192 = w1/w2 transpose tiles on the 64 otherwise-idle CUs.
//      mid = resid+LN2 only (h2 in-place over h). Workspace re-laid so
//      w1T/w2T live in dedicated regions; FFN2 partials split fp0/fp123.
// ---------------------------------------------------------------------------

typedef __bf16 bf16;
typedef __attribute__((ext_vector_type(8))) __bf16 bf16x8;
typedef __attribute__((ext_vector_type(4))) __bf16 bf16x4;
typedef __attribute__((ext_vector_type(4))) float f32x4;

#define DEV static __device__ __forceinline__

// Q pre-scale folded at QKV epilogue: (1/sqrt(128)) * log2(e)
#define QSCALE 0.12751741687f

DEV void gload_lds16(const void* gsrc, void* ldst) {
  typedef const __attribute__((address_space(1))) uint32_t gq_t;
  typedef __attribute__((address_space(3))) uint32_t lq_t;
  __builtin_amdgcn_global_load_lds((gq_t*)(uintptr_t)gsrc, (lq_t*)(uintptr_t)ldst,
                                   16, 0, 0);
}

DEV f32x4 mfma16(bf16x8 a, bf16x8 b, f32x4 c) {
  return __builtin_amdgcn_mfma_f32_16x16x32_bf16(a, b, c, 0, 0, 0);
}

// ---------------------------------------------------------------------------
// fused pre: blocks [0,4096) = LN1 row; [4096,7168) = qkv_w transpose tile.
// ---------------------------------------------------------------------------
__global__ __launch_bounds__(256) void pre_kernel(
    const float* __restrict__ x, const float* __restrict__ gw,
    const float* __restrict__ bw, bf16* __restrict__ hout,
    const float* __restrict__ qkv_w, bf16* __restrict__ wTq) {
  __shared__ float tile[32][33];
  __shared__ float red[8];
  int bid = blockIdx.x, t = threadIdx.x;
  if (bid < 4096) {
    int row = bid;
    const float* xr = x + (size_t)row * 1024;
    f32x4 v = *(const f32x4*)(xr + t * 4);
    float s = v[0] + v[1] + v[2] + v[3];
    float s2 = v[0] * v[0] + v[1] * v[1] + v[2] * v[2] + v[3] * v[3];
#pragma unroll
    for (int off = 1; off < 64; off <<= 1) {
      s += __shfl_xor(s, off);
      s2 += __shfl_xor(s2, off);
    }
    if ((t & 63) == 0) { red[t >> 6] = s; red[4 + (t >> 6)] = s2; }
    __syncthreads();
    s = red[0] + red[1] + red[2] + red[3];
    s2 = red[4] + red[5] + red[6] + red[7];
    float mu = s * (1.f / 1024.f);
    float rstd = rsqrtf(s2 * (1.f / 1024.f) - mu * mu + 1e-5f);
    f32x4 gv = *(const f32x4*)(gw + t * 4);
    f32x4 bv = *(const f32x4*)(bw + t * 4);
    bf16x4 o;
#pragma unroll
    for (int j = 0; j < 4; j++) o[j] = (bf16)((v[j] - mu) * rstd * gv[j] + bv[j]);
    *(bf16x4*)(hout + (size_t)row * 1024 + t * 4) = o;
  } else {
    int idx = bid - 4096;             // qkv_w [1024][3072] -> wTq [3072][1024]
    int c0 = (idx % 96) * 32, r0 = (idx / 96) * 32;
    int tx = t & 31, ty = t >> 5;
#pragma unroll
    for (int j = 0; j < 4; j++)
      tile[ty + 8 * j][tx] = qkv_w[(size_t)(r0 + ty + 8 * j) * 3072 + c0 + tx];
    __syncthreads();
#pragma unroll
    for (int j = 0; j < 4; j++)
      wTq[(size_t)(c0 + ty + 8 * j) * 1024 + r0 + tx] = (bf16)tile[tx][ty + 8 * j];
  }
}

// ---------------------------------------------------------------------------
// mid: resid+LN2 only. h2 written in-place over h (same element indices).
// ---------------------------------------------------------------------------
__global__ __launch_bounds__(256) void mid_kernel(
    const bf16* __restrict__ Op, const float* __restrict__ lbuf,
    const bf16* __restrict__ h, const float* __restrict__ gw,
    const float* __restrict__ bw, bf16* __restrict__ out) {
  __shared__ float red[8];
  int row = blockIdx.x, t = threadIdx.x;
  int head = t >> 5;
  float l = 0.f;
  float acc[4] = {0.f, 0.f, 0.f, 0.f};
#pragma unroll
  for (int z = 0; z < 2; z++) {
    l += lbuf[(size_t)(z * 8 + head) * 4096 + row];
    bf16x4 ov = *(const bf16x4*)(Op + (size_t)z * 4096 * 1024 +
                                 (size_t)row * 1024 + t * 4);
#pragma unroll
    for (int j = 0; j < 4; j++) acc[j] += (float)ov[j];
  }
  float rl = 1.0f / l;
  bf16x4 hv = *(const bf16x4*)(h + (size_t)row * 1024 + t * 4);
  float vv[4];
#pragma unroll
  for (int j = 0; j < 4; j++) vv[j] = acc[j] * rl + (float)hv[j];
  float s = vv[0] + vv[1] + vv[2] + vv[3];
  float s2 = vv[0] * vv[0] + vv[1] * vv[1] + vv[2] * vv[2] + vv[3] * vv[3];
#pragma unroll
  for (int off = 1; off < 64; off <<= 1) {
    s += __shfl_xor(s, off);
    s2 += __shfl_xor(s2, off);
  }
  if ((t & 63) == 0) { red[t >> 6] = s; red[4 + (t >> 6)] = s2; }
  __syncthreads();
  s = red[0] + red[1] + red[2] + red[3];
  s2 = red[4] + red[5] + red[6] + red[7];
  float mu = s * (1.f / 1024.f);
  float rstd = rsqrtf(s2 * (1.f / 1024.f) - mu * mu + 1e-5f);
  f32x4 gv = *(const f32x4*)(gw + t * 4);
  f32x4 bv = *(const f32x4*)(bw + t * 4);
  bf16x4 o;
#pragma unroll
  for (int j = 0; j < 4; j++) o[j] = (bf16)((vv[j] - mu) * rstd * gv[j] + bv[j]);
  *(bf16x4*)(out + (size_t)row * 1024 + t * 4) = o;
}

// ---------------------------------------------------------------------------
// FFN2 combine: out fp32 = fp0 + sum_{z=0..2} fp123[z] + b2. 1 block/row.
// ---------------------------------------------------------------------------
__global__ __launch_bounds__(256) void ffn2_combine_kernel(
    const bf16* __restrict__ P0, const bf16* __restrict__ P123,
    const float* __restrict__ b2, float* __restrict__ out) {
  int row = blockIdx.x, t = threadIdx.x;
  float acc[4];
  f32x4 bv = *(const f32x4*)(b2 + t * 4);
#pragma unroll
  for (int j = 0; j < 4; j++) acc[j] = bv[j];
  {
    bf16x4 pv = *(const bf16x4*)(P0 + (size_t)row * 1024 + t * 4);
#pragma unroll
    for (int j = 0; j < 4; j++) acc[j] += (float)pv[j];
  }
#pragma unroll
  for (int z = 0; z < 3; z++) {
    bf16x4 pv = *(const bf16x4*)(P123 + (size_t)z * 4096 * 1024 +
                                 (size_t)row * 1024 + t * 4);
#pragma unroll
    for (int j = 0; j < 4; j++) acc[j] += (float)pv[j];
  }
  f32x4 o = {acc[0], acc[1], acc[2], acc[3]};
  *(f32x4*)(out + (size_t)row * 1024 + t * 4) = o;
}

// ---------------------------------------------------------------------------
// 8-phase 256x256 GEMM (T3+T4 counted-vmcnt schedule): C = A @ Bt^T + bias.
// BK=64, 8 waves (2M x 4N), 512 thr, 128KB DYNAMIC LDS. K = row stride,
// Ks = K-slice per block (NT = Ks/64). EPILOG 4 = split-K partial (z from
// blockIdx.z, A/Bt pre-offset by caller per z-group), no bias, bf16 out.
// EPILOG 3 = QKV: 256 flat blocks; bid<192 GEMM (N=3072), bid>=192 =
//            w1/w2 transpose tail on the idle CUs.
// EPILOG 1 = GELU(tanh)+bf16.
// ---------------------------------------------------------------------------
template <int EPILOG>
__global__ __launch_bounds__(512) void gemm8p_kernel(
    const bf16* __restrict__ A, const bf16* __restrict__ Bt,
    const float* __restrict__ bias, bf16* __restrict__ Cout,
    bf16* __restrict__ Vout, int M, int N, int K, int Ks,
    const float* __restrict__ w1, bf16* __restrict__ w1T,
    const float* __restrict__ w2, bf16* __restrict__ w2T) {
  extern __shared__ char smem[];   // [0,64K) A bufs, [64K,128K) B bufs
  int bx, by;
  if constexpr (EPILOG == 3) {
    int bid = blockIdx.x;
    if (bid >= 192) {
      // ---- transpose tail: 64 blocks x 512 thr, 2 tiles/iter, 64 iters ----
      int t = threadIdx.x & 255, half = threadIdx.x >> 8;
      float* tl = (float*)(smem + half * 4352);   // 32x33 f32 = 4224B
      int tx = t & 31, ty = t >> 5;
      for (int it = 0; it < 64; it++) {
        int tile_idx = (bid - 192) * 128 + it * 2 + half;  // 0..8191
        const float* in; bf16* out; int R, C, c0, r0;
        if (tile_idx < 4096) {
          in = w1; out = w1T; R = 1024; C = 4096;
          c0 = (tile_idx & 127) * 32; r0 = (tile_idx >> 7) * 32;
        } else {
          int i2 = tile_idx - 4096;
          in = w2; out = w2T; R = 4096; C = 1024;
          c0 = (i2 & 31) * 32; r0 = (i2 >> 5) * 32;
        }
#pragma unroll
        for (int j = 0; j < 4; j++)
          tl[(ty + 8 * j) * 33 + tx] =
              in[(size_t)(r0 + ty + 8 * j) * C + c0 + tx];
        __syncthreads();
#pragma unroll
        for (int j = 0; j < 4; j++)
          out[(size_t)(c0 + ty + 8 * j) * R + r0 + tx] =
              (bf16)tl[tx * 33 + ty + 8 * j];
        __syncthreads();
      }
      return;
    }
    int swz = (bid & 7) * 24 + (bid >> 3);   // 192 blocks, 12x16 tiles
    bx = swz % 12; by = swz / 12;
  } else {
    if constexpr (EPILOG == 4) {
      size_t zo = (size_t)blockIdx.z * Ks;
      A += zo; Bt += zo;
      Cout += (size_t)blockIdx.z * ((size_t)M * N);
    }
    int nwg = gridDim.x * gridDim.y;
    int bid = blockIdx.y * gridDim.x + blockIdx.x;
    int swz = (bid & 7) * (nwg >> 3) + (bid >> 3);
    bx = swz % gridDim.x; by = swz / gridDim.x;
  }
  int m0 = by * 256, n0 = bx * 256;
  int tid = threadIdx.x, wave = tid >> 6, lane = tid & 63;
  int lr = lane & 15, lg = lane >> 4;
  int wr = (wave >> 2) * 128;
  int wc = (wave & 3) * 64;
  const int NT = Ks >> 6;

  f32x4 acc[8][4] = {};

  const int sArow = tid >> 3;
  const int scbA = ((tid & 7) * 16) ^ (((tid >> 3) & 7) << 4);
  const int scbB = ((lane & 7) * 16) ^ ((lane >> 3) << 4);

  auto stageA = [&](int c, int T) {
    char* sAb = smem + (size_t)(T & 1) * 32768;
#pragma unroll
    for (int j = 0; j < 2; j++) {
      int r0 = j * 128 + 64 * c;
      gload_lds16(A + (size_t)(m0 + r0 + sArow) * K + T * 64 + scbA / 2,
                  sAb + r0 * 128 + wave * 1024);
    }
  };
  auto stageB = [&](int c, int T) {
    char* sBb = smem + 65536 + (size_t)(T & 1) * 32768;
    int wrun = (wave >> 2) * 64 + 32 * c + (wave & 3) * 8;
#pragma unroll
    for (int j = 0; j < 2; j++) {
      int r0 = j * 128 + wrun;
      gload_lds16(Bt + (size_t)(n0 + r0 + (lane >> 3)) * K + T * 64 + scbB / 2,
                  sBb + r0 * 128);
    }
  };
  auto ldA = [&](bf16x8 (&af)[4][2], int qm, int b) {
    const char* sAb = smem + (size_t)b * 32768;
#pragma unroll
    for (int mm = 0; mm < 4; mm++)
#pragma unroll
      for (int kk = 0; kk < 2; kk++) {
        int rl = wr + 64 * qm + mm * 16 + lr;
        int db = (kk * 64 + lg * 16) ^ ((rl & 7) << 4);
        af[mm][kk] = *(const bf16x8*)(sAb + rl * 128 + db);
      }
  };
  auto ldB = [&](bf16x8 (&bfv)[2][2], int qn, int b) {
    const char* sBb = smem + 65536 + (size_t)b * 32768;
#pragma unroll
    for (int nn = 0; nn < 2; nn++)
#pragma unroll
      for (int kk = 0; kk < 2; kk++) {
        int rb = wc + 32 * qn + nn * 16 + lr;
        int db = (kk * 64 + lg * 16) ^ ((rb & 7) << 4);
        bfv[nn][kk] = *(const bf16x8*)(sBb + rb * 128 + db);
      }
  };
  auto mfmaQ = [&](bf16x8 (&af)[4][2], bf16x8 (&bfv)[2][2], int qm, int qn) {
    __builtin_amdgcn_s_setprio(1);
#pragma unroll
    for (int kk = 0; kk < 2; kk++)
#pragma unroll
      for (int mm = 0; mm < 4; mm++)
#pragma unroll
        for (int nn = 0; nn < 2; nn++)
          acc[qm * 4 + mm][qn * 2 + nn] =
              mfma16(af[mm][kk], bfv[nn][kk], acc[qm * 4 + mm][qn * 2 + nn]);
    __builtin_amdgcn_s_setprio(0);
  };

  stageA(0, 0); stageB(0, 0); stageA(1, 0); stageB(1, 0);
  stageA(0, 1); stageB(0, 1);
  asm volatile("s_waitcnt vmcnt(4)" ::: "memory");
  __builtin_amdgcn_s_barrier();

  for (int T = 0; T < NT; T++) {
    int b = T & 1;
    bf16x8 af[4][2], bfv[2][2];
    ldA(af, 0, b); ldB(bfv, 0, b);
    if (T + 1 < NT) stageA(1, T + 1);
    __builtin_amdgcn_s_barrier();
    mfmaQ(af, bfv, 0, 0);
    __builtin_amdgcn_s_barrier();
    ldB(bfv, 1, b);
    if (T + 1 < NT) stageB(1, T + 1);
    __builtin_amdgcn_s_barrier();
    mfmaQ(af, bfv, 0, 1);
    __builtin_amdgcn_s_barrier();
    ldA(af, 1, b); ldB(bfv, 0, b);
    if (T + 2 < NT) stageA(0, T + 2);
    __builtin_amdgcn_s_barrier();
    mfmaQ(af, bfv, 1, 0);
    __builtin_amdgcn_s_barrier();
    ldB(bfv, 1, b);
    if (T + 2 < NT) stageB(0, T + 2);
    __builtin_amdgcn_s_barrier();
    mfmaQ(af, bfv, 1, 1);
    if (T < NT - 2) asm volatile("s_waitcnt vmcnt(4)" ::: "memory");
    else            asm volatile("s_waitcnt vmcnt(0)" ::: "memory");
    __builtin_amdgcn_s_barrier();
  }

#pragma unroll
  for (int n = 0; n < 4; n++) {
    int col = n0 + wc + n * 16 + lr;
    float bs = (EPILOG == 4) ? 0.f : bias[col];
#pragma unroll
    for (int m = 0; m < 8; m++) {
      int row0 = m0 + wr + m * 16 + lg * 4;
      if constexpr (EPILOG == 3) {
        if (col >= 2048) {
          bf16x4 pk;
#pragma unroll
          for (int r = 0; r < 4; r++) pk[r] = (bf16)(acc[m][n][r] + bs);
          *(bf16x4*)(Vout + (size_t)(col - 2048) * 4096 + row0) = pk;
          continue;
        }
      }
#pragma unroll
      for (int r = 0; r < 4; r++) {
        float v = acc[m][n][r] + bs;
        if constexpr (EPILOG == 1) {
          float u = v + 0.044715f * v * v * v;
          float e = __builtin_amdgcn_exp2f(-2.3021144f * u);
          v = v / (1.0f + e);
        }
        if constexpr (EPILOG == 3) { if (col < 1024) v *= QSCALE; }
        Cout[(size_t)(row0 + r) * N + col] = (bf16)v;
      }
    }
  }
}

// ---------------------------------------------------------------------------
// Flash attention, KV-split x2, 32 q rows per wave (QBLK=128 per block).
// grid (32 qtiles, 8 heads, 2 kv-halves) = 512 blocks = exactly 2/CU.
// R13 dbuf (80KB dynamic LDS, prefetch-before-compute) + R14 nf-pair QK.
// ---------------------------------------------------------------------------
__global__ __launch_bounds__(256) void attn_kernel(
    const bf16* __restrict__ qkv, const bf16* __restrict__ vt,
    bf16* __restrict__ opart, float* __restrict__ lbuf) {
  constexpr int S = 4096, C3 = 3072;
  extern __shared__ char asmem[];   // [0,32K) sK[2], [32,64K) sV[2], [64,80K) sP
  int hh = blockIdx.y;
  int q0 = blockIdx.x * 128;
  int z = blockIdx.z;
  int kv_begin = z * (S / 2), kv_end = kv_begin + (S / 2);
  bf16* obuf = opart + (size_t)z * 4096 * 1024;
  int tid = threadIdx.x, wave = tid >> 6, lane = tid & 63;
  int lr = lane & 15, lg = lane >> 4;

  bf16x8 qf[2][4];
#pragma unroll
  for (int qs = 0; qs < 2; qs++) {
    const bf16* qrow =
        qkv + (size_t)(q0 + wave * 32 + qs * 16 + lr) * C3 + hh * 128 + lg * 8;
#pragma unroll
    for (int kk = 0; kk < 4; kk++) qf[qs][kk] = *(const bf16x8*)(qrow + kk * 32);
  }
  f32x4 o[2][8] = {};
  float lsum[2] = {0.f, 0.f};

  const int krow_s = tid >> 4;
  const int kcb = (tid & 15) * 16;
  const int scbK = kcb ^ ((krow_s & 7) << 4);
  const int vrow_s = tid >> 3;
  const int vcb = (tid & 7) * 16;
  const int scbV = vcb ^ ((vrow_s & 7) << 4);

  const bf16* kbase = qkv + 1024 + hh * 128 + scbK / 2;
  const bf16* vbase = vt + (size_t)(hh * 128 + vrow_s) * S + scbV / 2;

  char* pw = asmem + 65536 + wave * 4096;

#define STAGE(B, KV0)                                                        \
  do {                                                                       \
    _Pragma("unroll") for (int i = 0; i < 4; i++)                            \
        gload_lds16(kbase + (size_t)((KV0) + i * 16 + krow_s) * C3,          \
                    asmem + (B) * 16384 + i * 4096 + wave * 1024);           \
    _Pragma("unroll") for (int i = 0; i < 4; i++)                            \
        gload_lds16(vbase + (size_t)(i * 32) * S + (KV0),                    \
                    asmem + 32768 + (B) * 16384 + i * 4096 + wave * 1024);   \
  } while (0)

  STAGE(0, kv_begin);
  __syncthreads();
  int buf = 0;

  for (int kv0 = kv_begin; kv0 < kv_end; kv0 += 64) {
    if (kv0 + 64 < kv_end) STAGE(buf ^ 1, kv0 + 64);

    const char* sKb = asmem + buf * 16384;
    const char* sVb = asmem + 32768 + buf * 16384;

#pragma unroll
    for (int nfp = 0; nfp < 2; nfp++) {
      f32x4 s00 = {0.f, 0.f, 0.f, 0.f}, s01 = s00, s10 = s00, s11 = s00;
      __builtin_amdgcn_s_setprio(1);
#pragma unroll
      for (int kk = 0; kk < 4; kk++) {
        int kr0 = (nfp * 2 + 0) * 16 + lr;
        int kr1 = (nfp * 2 + 1) * 16 + lr;
        int db0 = (kk * 64 + lg * 16) ^ ((kr0 & 7) << 4);
        int db1 = (kk * 64 + lg * 16) ^ ((kr1 & 7) << 4);
        bf16x8 kf0 = *(const bf16x8*)(sKb + kr0 * 256 + db0);
        bf16x8 kf1 = *(const bf16x8*)(sKb + kr1 * 256 + db1);
        s00 = mfma16(kf0, qf[0][kk], s00);
        s01 = mfma16(kf0, qf[1][kk], s01);
        s10 = mfma16(kf1, qf[0][kk], s10);
        s11 = mfma16(kf1, qf[1][kk], s11);
      }
      __builtin_amdgcn_s_setprio(0);
      f32x4 scs[2][2] = {{s00, s01}, {s10, s11}};
#pragma unroll
      for (int nfh = 0; nfh < 2; nfh++) {
        int nf = nfp * 2 + nfh;
#pragma unroll
        for (int qs = 0; qs < 2; qs++) {
          float p0 = __builtin_amdgcn_exp2f(scs[nfh][qs][0]);
          float p1 = __builtin_amdgcn_exp2f(scs[nfh][qs][1]);
          float p2 = __builtin_amdgcn_exp2f(scs[nfh][qs][2]);
          float p3 = __builtin_amdgcn_exp2f(scs[nfh][qs][3]);
          lsum[qs] += (p0 + p1) + (p2 + p3);
          bf16x4 pk;
          pk[0] = (bf16)p0; pk[1] = (bf16)p1; pk[2] = (bf16)p2; pk[3] = (bf16)p3;
          *(bf16x4*)(pw + (qs * 16 + lr) * 128 +
                     ((nf * 32 + lg * 8) ^ ((lr & 7) << 4))) = pk;
        }
      }
    }

    bf16x8 pa[2][2];
#pragma unroll
    for (int qs = 0; qs < 2; qs++)
#pragma unroll
      for (int kk = 0; kk < 2; kk++) {
        int db = (kk * 64 + lg * 16) ^ ((lr & 7) << 4);
        pa[qs][kk] = *(const bf16x8*)(pw + (qs * 16 + lr) * 128 + db);
      }
    __builtin_amdgcn_s_setprio(1);
#pragma unroll
    for (int df = 0; df < 8; df++) {
#pragma unroll
      for (int kk = 0; kk < 2; kk++) {
        int vrow = df * 16 + lr;
        int db = (kk * 64 + lg * 16) ^ ((vrow & 7) << 4);
        bf16x8 vf = *(const bf16x8*)(sVb + vrow * 128 + db);
        o[0][df] = mfma16(pa[0][kk], vf, o[0][df]);
        o[1][df] = mfma16(pa[1][kk], vf, o[1][df]);
      }
    }
    __builtin_amdgcn_s_setprio(0);
    __syncthreads();
    buf ^= 1;
  }
#undef STAGE

#pragma unroll
  for (int qs = 0; qs < 2; qs++) {
    float ls = lsum[qs];
    ls += __shfl_xor(ls, 16);
    ls += __shfl_xor(ls, 32);
    if (lg == 0)
      lbuf[(size_t)(z * 8 + hh) * 4096 + q0 + wave * 32 + qs * 16 + lr] = ls;
#pragma unroll
    for (int df = 0; df < 8; df++) {
      int col = hh * 128 + df * 16 + lr;
#pragma unroll
      for (int r = 0; r < 4; r++) {
        int row = q0 + wave * 32 + qs * 16 + lg * 4 + r;
        obuf[(size_t)row * 1024 + col] = (bf16)o[qs][df][r];
      }
    }
  }
}

// ---------------------------------------------------------------------------
// Launch. Workspace layout (peak 78.5 MB), liveness-verified:
//   [0,8M)    h (pre -> mid; h2 in-place) -> fp0 (FFN2 z=0)
//   [8,32M)   qkv (QKV -> attn) -> ffn1 [8,40M) after mid
//   [32,40M)  vt (QKV -> attn) -> ffn1 tail
//   [40,56M)  Op 2x8MB (attn -> mid) -> fp123 z=1,2 (FFN2)
//   [56,64M)  w1T (QKV tail -> ffn1) -> fp123 z=3 (FFN2; w1T dead)
//   [64,72M)  w2T (QKV tail -> FFN2, live THROUGH FFN2 - not aliased)
//   [72,72.5M) lbuf | [72.5,78.5M) wTq
// ---------------------------------------------------------------------------
extern "C" void kernel_launch(void* const* d_in, const int* in_sizes, int n_in,
                              void* d_out, int out_size, void* d_ws, size_t ws_size,
                              hipStream_t stream) {
  const float* x     = (const float*)d_in[0];
  const float* ln1_g = (const float*)d_in[1];
  const float* ln1_b = (const float*)d_in[2];
  const float* qkv_w = (const float*)d_in[3];
  const float* qkv_b = (const float*)d_in[4];
  const float* ln2_g = (const float*)d_in[5];
  const float* ln2_b = (const float*)d_in[6];
  const float* w1    = (const float*)d_in[7];
  const float* b1    = (const float*)d_in[8];
  const float* w2    = (const float*)d_in[9];
  const float* b2    = (const float*)d_in[10];

  char* ws = (char*)d_ws;
  const size_t MB = 1ull << 20;
  bf16*  h     = (bf16*)(ws + 0);
  bf16*  h2    = (bf16*)(ws + 0);          // in-place over h
  bf16*  fp0   = (bf16*)(ws + 0);          // FFN2 z=0 partial (h2 dead)
  bf16*  qkv   = (bf16*)(ws + 8 * MB);
  bf16*  ffn1  = (bf16*)(ws + 8 * MB);     // after attn (qkv+vt dead)
  bf16*  vt    = (bf16*)(ws + 32 * MB);
  bf16*  Op    = (bf16*)(ws + 40 * MB);    // 2 x 8MB (attn -> mid)
  bf16*  fp123 = (bf16*)(ws + 40 * MB);    // FFN2 z=1..3 (Op+w1T dead)
  bf16*  w1T   = (bf16*)(ws + 56 * MB);
  bf16*  w2T   = (bf16*)(ws + 64 * MB);
  float* lbuf  = (float*)(ws + 72 * MB);
  bf16*  wTq   = (bf16*)(ws + 72 * MB + 512 * 1024);
  float* outp  = (float*)d_out;

  hipFuncSetAttribute(reinterpret_cast<const void*>(gemm8p_kernel<3>),
                      hipFuncAttributeMaxDynamicSharedMemorySize, 131072);
  hipFuncSetAttribute(reinterpret_cast<const void*>(gemm8p_kernel<1>),
                      hipFuncAttributeMaxDynamicSharedMemorySize, 131072);
  hipFuncSetAttribute(reinterpret_cast<const void*>(gemm8p_kernel<4>),
                      hipFuncAttributeMaxDynamicSharedMemorySize, 131072);
  hipFuncSetAttribute(reinterpret_cast<const void*>(attn_kernel),
                      hipFuncAttributeMaxDynamicSharedMemorySize, 81920);

  // 1. LN1 + qkv_w transpose (fused)
  pre_kernel<<<7168, 256, 0, stream>>>(x, ln1_g, ln1_b, h, qkv_w, wTq);
  // 2. QKV GEMM (192 blocks) + w1/w2 transposes (64 tail blocks)
  gemm8p_kernel<3><<<256, 512, 131072, stream>>>(
      h, wTq, qkv_b, qkv, vt, 4096, 3072, 1024, 1024, w1, w1T, w2, w2T);
  // 3. attention, KV-split x2 -> bf16 O partials + l
  attn_kernel<<<dim3(32, 8, 2), 256, 81920, stream>>>(qkv, vt, Op, lbuf);
  // 4. resid + LN2 (h2 in-place over h)
  mid_kernel<<<4096, 256, 0, stream>>>(Op, lbuf, h, ln2_g, ln2_b, h2);
  // 5. ffn1 = gelu(h2 @ w1 + b1)
  gemm8p_kernel<1><<<dim3(4096 / 256, 4096 / 256), 512, 131072, stream>>>(
      h2, w1T, b1, ffn1, nullptr, 4096, 4096, 1024, 1024,
      nullptr, nullptr, nullptr, nullptr);
  // 6a. FFN2 z=0 -> fp0 (over h2, dead after FFN1 reads it... FFN1 READS h2
  //     and this launch runs after FFN1 completes: safe)
  gemm8p_kernel<4><<<dim3(1024 / 256, 4096 / 256, 1), 512, 131072, stream>>>(
      ffn1, w2T, nullptr, fp0, nullptr, 4096, 1024, 4096, 1024,
      nullptr, nullptr, nullptr, nullptr);
  // 6b. FFN2 z=1..3 -> fp123 (A/Bt offset by 1 slice; blockIdx.z adds more)
  gemm8p_kernel<4><<<dim3(1024 / 256, 4096 / 256, 3), 512, 131072, stream>>>(
      ffn1 + 1024, w2T + 1024, nullptr, fp123, nullptr, 4096, 1024, 4096, 1024,
      nullptr, nullptr, nullptr, nullptr);
  // 7. out = fp0 + sum fp123 + b2 (fp32)
  ffn2_combine_kernel<<<4096, 256, 0, stream>>>(fp0, fp123, b2, outp);
}

// Round 17
// 232.262 us; speedup vs baseline: 1.1140x; 1.1140x over previous
//
#include <hip/hip_runtime.h>
#include <stdint.h>

// ---------------------------------------------------------------------------
// EncoderBlock: LN1 -> QKV GEMM -> MHA (flash) -> +resid -> LN2 -> FFN(GELU)
// bf16 MFMA (16x16x32), fp32 accumulate. S=4096, D=1024, H=8, hd=128, FF=4096.
// R17: full revert to R15 (best: 232.9us). R16's FFN2 two-launch split
//      serialized the split-K slices (64-block launch = 75% idle GPU for a
//      full slice) and cost +26us. R15 structure: pre(LN1+qkv_w^T), QKV GEMM
//      192 blocks, attn KV-split x2, mid(w1/w2^T + resid+LN2), FFN1, FFN2
//      split-K x4 in ONE 256-block launch, combine.
// ---------------------------------------------------------------------------

typedef __bf16 bf16;
typedef __attribute__((ext_vector_type(8))) __bf16 bf16x8;
typedef __attribute__((ext_vector_type(4))) __bf16 bf16x4;
typedef __attribute__((ext_vector_type(4))) float f32x4;

#define DEV static __device__ __forceinline__

// Q pre-scale folded at QKV epilogue: (1/sqrt(128)) * log2(e)
#define QSCALE 0.12751741687f

DEV void gload_lds16(const void* gsrc, void* ldst) {
  typedef const __attribute__((address_space(1))) uint32_t gq_t;
  typedef __attribute__((address_space(3))) uint32_t lq_t;
  __builtin_amdgcn_global_load_lds((gq_t*)(uintptr_t)gsrc, (lq_t*)(uintptr_t)ldst,
                                   16, 0, 0);
}

DEV f32x4 mfma16(bf16x8 a, bf16x8 b, f32x4 c) {
  return __builtin_amdgcn_mfma_f32_16x16x32_bf16(a, b, c, 0, 0, 0);
}

// ---------------------------------------------------------------------------
// fused pre: blocks [0,4096) = LN1 row; [4096,7168) = qkv_w transpose tile.
// ---------------------------------------------------------------------------
__global__ __launch_bounds__(256) void pre_kernel(
    const float* __restrict__ x, const float* __restrict__ gw,
    const float* __restrict__ bw, bf16* __restrict__ hout,
    const float* __restrict__ qkv_w, bf16* __restrict__ wTq) {
  __shared__ float tile[32][33];
  __shared__ float red[8];
  int bid = blockIdx.x, t = threadIdx.x;
  if (bid < 4096) {
    int row = bid;
    const float* xr = x + (size_t)row * 1024;
    f32x4 v = *(const f32x4*)(xr + t * 4);
    float s = v[0] + v[1] + v[2] + v[3];
    float s2 = v[0] * v[0] + v[1] * v[1] + v[2] * v[2] + v[3] * v[3];
#pragma unroll
    for (int off = 1; off < 64; off <<= 1) {
      s += __shfl_xor(s, off);
      s2 += __shfl_xor(s2, off);
    }
    if ((t & 63) == 0) { red[t >> 6] = s; red[4 + (t >> 6)] = s2; }
    __syncthreads();
    s = red[0] + red[1] + red[2] + red[3];
    s2 = red[4] + red[5] + red[6] + red[7];
    float mu = s * (1.f / 1024.f);
    float rstd = rsqrtf(s2 * (1.f / 1024.f) - mu * mu + 1e-5f);
    f32x4 gv = *(const f32x4*)(gw + t * 4);
    f32x4 bv = *(const f32x4*)(bw + t * 4);
    bf16x4 o;
#pragma unroll
    for (int j = 0; j < 4; j++) o[j] = (bf16)((v[j] - mu) * rstd * gv[j] + bv[j]);
    *(bf16x4*)(hout + (size_t)row * 1024 + t * 4) = o;
  } else {
    int idx = bid - 4096;             // qkv_w [1024][3072] -> wTq [3072][1024]
    int c0 = (idx % 96) * 32, r0 = (idx / 96) * 32;
    int tx = t & 31, ty = t >> 5;
#pragma unroll
    for (int j = 0; j < 4; j++)
      tile[ty + 8 * j][tx] = qkv_w[(size_t)(r0 + ty + 8 * j) * 3072 + c0 + tx];
    __syncthreads();
#pragma unroll
    for (int j = 0; j < 4; j++)
      wTq[(size_t)(c0 + ty + 8 * j) * 1024 + r0 + tx] = (bf16)tile[tx][ty + 8 * j];
  }
}

// ---------------------------------------------------------------------------
// fused mid: blocks [0,4096) w1 transpose; [4096,8192) w2 transpose;
//            [8192,12288) resid+LN2 row (2 kv-split partials).
// ---------------------------------------------------------------------------
__global__ __launch_bounds__(256) void mid_kernel(
    const float* __restrict__ w1, bf16* __restrict__ w1T,
    const float* __restrict__ w2, bf16* __restrict__ w2T,
    const bf16* __restrict__ Op, const float* __restrict__ lbuf,
    const bf16* __restrict__ h, const float* __restrict__ gw,
    const float* __restrict__ bw, bf16* __restrict__ out) {
  __shared__ float tile[32][33];
  __shared__ float red[8];
  int bid = blockIdx.x, t = threadIdx.x;
  if (bid < 8192) {
    const float* in; bf16* outp; int R, C, c0, r0;
    if (bid < 4096) {
      in = w1; outp = w1T; R = 1024; C = 4096;
      c0 = (bid & 127) * 32; r0 = (bid >> 7) * 32;
    } else {
      int idx = bid - 4096;
      in = w2; outp = w2T; R = 4096; C = 1024;
      c0 = (idx & 31) * 32; r0 = (idx >> 5) * 32;
    }
    int tx = t & 31, ty = t >> 5;
#pragma unroll
    for (int j = 0; j < 4; j++)
      tile[ty + 8 * j][tx] = in[(size_t)(r0 + ty + 8 * j) * C + c0 + tx];
    __syncthreads();
#pragma unroll
    for (int j = 0; j < 4; j++)
      outp[(size_t)(c0 + ty + 8 * j) * R + r0 + tx] = (bf16)tile[tx][ty + 8 * j];
  } else {
    int row = bid - 8192;
    int head = t >> 5;
    float l = 0.f;
    float acc[4] = {0.f, 0.f, 0.f, 0.f};
#pragma unroll
    for (int z = 0; z < 2; z++) {
      l += lbuf[(size_t)(z * 8 + head) * 4096 + row];
      bf16x4 ov = *(const bf16x4*)(Op + (size_t)z * 4096 * 1024 +
                                   (size_t)row * 1024 + t * 4);
#pragma unroll
      for (int j = 0; j < 4; j++) acc[j] += (float)ov[j];
    }
    float rl = 1.0f / l;
    bf16x4 hv = *(const bf16x4*)(h + (size_t)row * 1024 + t * 4);
    float vv[4];
#pragma unroll
    for (int j = 0; j < 4; j++) vv[j] = acc[j] * rl + (float)hv[j];
    float s = vv[0] + vv[1] + vv[2] + vv[3];
    float s2 = vv[0] * vv[0] + vv[1] * vv[1] + vv[2] * vv[2] + vv[3] * vv[3];
#pragma unroll
    for (int off = 1; off < 64; off <<= 1) {
      s += __shfl_xor(s, off);
      s2 += __shfl_xor(s2, off);
    }
    if ((t & 63) == 0) { red[t >> 6] = s; red[4 + (t >> 6)] = s2; }
    __syncthreads();
    s = red[0] + red[1] + red[2] + red[3];
    s2 = red[4] + red[5] + red[6] + red[7];
    float mu = s * (1.f / 1024.f);
    float rstd = rsqrtf(s2 * (1.f / 1024.f) - mu * mu + 1e-5f);
    f32x4 gv = *(const f32x4*)(gw + t * 4);
    f32x4 bv = *(const f32x4*)(bw + t * 4);
    bf16x4 o;
#pragma unroll
    for (int j = 0; j < 4; j++) o[j] = (bf16)((vv[j] - mu) * rstd * gv[j] + bv[j]);
    *(bf16x4*)(out + (size_t)row * 1024 + t * 4) = o;
  }
}

// ---------------------------------------------------------------------------
// FFN2 combine: out fp32 = sum_z partial_z (bf16) + b2. One block per row.
// ---------------------------------------------------------------------------
__global__ __launch_bounds__(256) void ffn2_combine_kernel(
    const bf16* __restrict__ P, const float* __restrict__ b2,
    float* __restrict__ out) {
  int row = blockIdx.x, t = threadIdx.x;
  float acc[4];
  f32x4 bv = *(const f32x4*)(b2 + t * 4);
#pragma unroll
  for (int j = 0; j < 4; j++) acc[j] = bv[j];
#pragma unroll
  for (int z = 0; z < 4; z++) {
    bf16x4 pv = *(const bf16x4*)(P + (size_t)z * 4096 * 1024 +
                                 (size_t)row * 1024 + t * 4);
#pragma unroll
    for (int j = 0; j < 4; j++) acc[j] += (float)pv[j];
  }
  f32x4 o = {acc[0], acc[1], acc[2], acc[3]};
  *(f32x4*)(out + (size_t)row * 1024 + t * 4) = o;
}

// ---------------------------------------------------------------------------
// 8-phase 256x256 GEMM (T3+T4 counted-vmcnt schedule): C = A @ Bt^T + bias.
// BK=64, 8 waves (2M x 4N), 512 thr, 128KB DYNAMIC LDS. K = row stride,
// Ks = K-slice length per block (NT = Ks/64). EPILOG 4 = split-K: block z
// handles A[.., z*Ks..], Bt[.., z*Ks..] -> bf16 partial at Cout + z*M*N.
// EPILOG: 1 = GELU(tanh)+bf16 | 3 = QKV (Q-scale col<1024, V>=2048 transposed)
// ---------------------------------------------------------------------------
template <int EPILOG>
__global__ __launch_bounds__(512) void gemm8p_kernel(
    const bf16* __restrict__ A, const bf16* __restrict__ Bt,
    const float* __restrict__ bias, bf16* __restrict__ Cout,
    bf16* __restrict__ Vout, int M, int N, int K, int Ks) {
  extern __shared__ char smem[];   // [0,64K) A bufs, [64K,128K) B bufs
  if constexpr (EPILOG == 4) {
    size_t zo = (size_t)blockIdx.z * Ks;
    A += zo; Bt += zo;
    Cout += (size_t)blockIdx.z * ((size_t)M * N);
  }
  int nwg = gridDim.x * gridDim.y;
  int bid = blockIdx.y * gridDim.x + blockIdx.x;
  int swz = (bid & 7) * (nwg >> 3) + (bid >> 3);
  int bx = swz % gridDim.x, by = swz / gridDim.x;
  int m0 = by * 256, n0 = bx * 256;
  int tid = threadIdx.x, wave = tid >> 6, lane = tid & 63;
  int lr = lane & 15, lg = lane >> 4;
  int wr = (wave >> 2) * 128;      // 2 M-groups of waves
  int wc = (wave & 3) * 64;        // 4 N-groups
  const int NT = Ks >> 6;

  f32x4 acc[8][4] = {};

  const int sArow = tid >> 3;                                  // 0..63
  const int scbA = ((tid & 7) * 16) ^ (((tid >> 3) & 7) << 4); // byte col
  const int scbB = ((lane & 7) * 16) ^ ((lane >> 3) << 4);

  auto stageA = [&](int c, int T) {
    char* sAb = smem + (size_t)(T & 1) * 32768;
#pragma unroll
    for (int j = 0; j < 2; j++) {
      int r0 = j * 128 + 64 * c;
      gload_lds16(A + (size_t)(m0 + r0 + sArow) * K + T * 64 + scbA / 2,
                  sAb + r0 * 128 + wave * 1024);
    }
  };
  auto stageB = [&](int c, int T) {
    char* sBb = smem + 65536 + (size_t)(T & 1) * 32768;
    int wrun = (wave >> 2) * 64 + 32 * c + (wave & 3) * 8;
#pragma unroll
    for (int j = 0; j < 2; j++) {
      int r0 = j * 128 + wrun;
      gload_lds16(Bt + (size_t)(n0 + r0 + (lane >> 3)) * K + T * 64 + scbB / 2,
                  sBb + r0 * 128);
    }
  };
  auto ldA = [&](bf16x8 (&af)[4][2], int qm, int b) {
    const char* sAb = smem + (size_t)b * 32768;
#pragma unroll
    for (int mm = 0; mm < 4; mm++)
#pragma unroll
      for (int kk = 0; kk < 2; kk++) {
        int rl = wr + 64 * qm + mm * 16 + lr;
        int db = (kk * 64 + lg * 16) ^ ((rl & 7) << 4);
        af[mm][kk] = *(const bf16x8*)(sAb + rl * 128 + db);
      }
  };
  auto ldB = [&](bf16x8 (&bfv)[2][2], int qn, int b) {
    const char* sBb = smem + 65536 + (size_t)b * 32768;
#pragma unroll
    for (int nn = 0; nn < 2; nn++)
#pragma unroll
      for (int kk = 0; kk < 2; kk++) {
        int rb = wc + 32 * qn + nn * 16 + lr;
        int db = (kk * 64 + lg * 16) ^ ((rb & 7) << 4);
        bfv[nn][kk] = *(const bf16x8*)(sBb + rb * 128 + db);
      }
  };
  auto mfmaQ = [&](bf16x8 (&af)[4][2], bf16x8 (&bfv)[2][2], int qm, int qn) {
    __builtin_amdgcn_s_setprio(1);
#pragma unroll
    for (int kk = 0; kk < 2; kk++)
#pragma unroll
      for (int mm = 0; mm < 4; mm++)
#pragma unroll
        for (int nn = 0; nn < 2; nn++)
          acc[qm * 4 + mm][qn * 2 + nn] =
              mfma16(af[mm][kk], bfv[nn][kk], acc[qm * 4 + mm][qn * 2 + nn]);
    __builtin_amdgcn_s_setprio(0);
  };

  // prologue: tile0 complete + A0/B0 of tile1
  stageA(0, 0); stageB(0, 0); stageA(1, 0); stageB(1, 0);
  stageA(0, 1); stageB(0, 1);
  asm volatile("s_waitcnt vmcnt(4)" ::: "memory");
  __builtin_amdgcn_s_barrier();

  for (int T = 0; T < NT; T++) {
    int b = T & 1;
    bf16x8 af[4][2], bfv[2][2];
    ldA(af, 0, b); ldB(bfv, 0, b);
    if (T + 1 < NT) stageA(1, T + 1);
    __builtin_amdgcn_s_barrier();
    mfmaQ(af, bfv, 0, 0);
    __builtin_amdgcn_s_barrier();
    ldB(bfv, 1, b);
    if (T + 1 < NT) stageB(1, T + 1);
    __builtin_amdgcn_s_barrier();
    mfmaQ(af, bfv, 0, 1);
    __builtin_amdgcn_s_barrier();
    ldA(af, 1, b); ldB(bfv, 0, b);
    if (T + 2 < NT) stageA(0, T + 2);
    __builtin_amdgcn_s_barrier();
    mfmaQ(af, bfv, 1, 0);
    __builtin_amdgcn_s_barrier();
    ldB(bfv, 1, b);
    if (T + 2 < NT) stageB(0, T + 2);
    __builtin_amdgcn_s_barrier();
    mfmaQ(af, bfv, 1, 1);
    if (T < NT - 2) asm volatile("s_waitcnt vmcnt(4)" ::: "memory");
    else            asm volatile("s_waitcnt vmcnt(0)" ::: "memory");
    __builtin_amdgcn_s_barrier();
  }

#pragma unroll
  for (int n = 0; n < 4; n++) {
    int col = n0 + wc + n * 16 + lr;
    float bs = (EPILOG == 4) ? 0.f : bias[col];
#pragma unroll
    for (int m = 0; m < 8; m++) {
      int row0 = m0 + wr + m * 16 + lg * 4;
      if constexpr (EPILOG == 3) {
        if (col >= 2048) {
          bf16x4 pk;
#pragma unroll
          for (int r = 0; r < 4; r++) pk[r] = (bf16)(acc[m][n][r] + bs);
          *(bf16x4*)(Vout + (size_t)(col - 2048) * 4096 + row0) = pk;
          continue;
        }
      }
#pragma unroll
      for (int r = 0; r < 4; r++) {
        float v = acc[m][n][r] + bs;
        if constexpr (EPILOG == 1) {
          float u = v + 0.044715f * v * v * v;
          float e = __builtin_amdgcn_exp2f(-2.3021144f * u);
          v = v / (1.0f + e);
        }
        if constexpr (EPILOG == 3) { if (col < 1024) v *= QSCALE; }
        Cout[(size_t)(row0 + r) * N + col] = (bf16)v;
      }
    }
  }
}

// ---------------------------------------------------------------------------
// Flash attention, KV-split x2, 32 q rows per wave (QBLK=128 per block).
// grid (32 qtiles, 8 heads, 2 kv-halves) = 512 blocks = exactly 2/CU, one
// scheduling round. R13 dbuf (80KB dynamic LDS, prefetch-before-compute) +
// R14 nf-pair QK (4 independent 4-deep MFMA chains).
// Static max (m=0, exp2 units); l deferred; unnormalized bf16 O + l partials.
// S^T = K @ Q^T swapped MFMA; XOR swizzle both-sides (rule 21).
// ---------------------------------------------------------------------------
__global__ __launch_bounds__(256) void attn_kernel(
    const bf16* __restrict__ qkv, const bf16* __restrict__ vt,
    bf16* __restrict__ opart, float* __restrict__ lbuf) {
  constexpr int S = 4096, C3 = 3072;
  extern __shared__ char asmem[];   // [0,32K) sK[2], [32,64K) sV[2], [64,80K) sP
  int hh = blockIdx.y;
  int q0 = blockIdx.x * 128;
  int z = blockIdx.z;
  int kv_begin = z * (S / 2), kv_end = kv_begin + (S / 2);
  bf16* obuf = opart + (size_t)z * 4096 * 1024;
  int tid = threadIdx.x, wave = tid >> 6, lane = tid & 63;
  int lr = lane & 15, lg = lane >> 4;

  bf16x8 qf[2][4];
#pragma unroll
  for (int qs = 0; qs < 2; qs++) {
    const bf16* qrow =
        qkv + (size_t)(q0 + wave * 32 + qs * 16 + lr) * C3 + hh * 128 + lg * 8;
#pragma unroll
    for (int kk = 0; kk < 4; kk++) qf[qs][kk] = *(const bf16x8*)(qrow + kk * 32);
  }
  f32x4 o[2][8] = {};
  float lsum[2] = {0.f, 0.f};

  const int krow_s = tid >> 4;
  const int kcb = (tid & 15) * 16;
  const int scbK = kcb ^ ((krow_s & 7) << 4);
  const int vrow_s = tid >> 3;
  const int vcb = (tid & 7) * 16;
  const int scbV = vcb ^ ((vrow_s & 7) << 4);

  const bf16* kbase = qkv + 1024 + hh * 128 + scbK / 2;
  const bf16* vbase = vt + (size_t)(hh * 128 + vrow_s) * S + scbV / 2;

  char* pw = asmem + 65536 + wave * 4096;

#define STAGE(B, KV0)                                                        \
  do {                                                                       \
    _Pragma("unroll") for (int i = 0; i < 4; i++)                            \
        gload_lds16(kbase + (size_t)((KV0) + i * 16 + krow_s) * C3,          \
                    asmem + (B) * 16384 + i * 4096 + wave * 1024);           \
    _Pragma("unroll") for (int i = 0; i < 4; i++)                            \
        gload_lds16(vbase + (size_t)(i * 32) * S + (KV0),                    \
                    asmem + 32768 + (B) * 16384 + i * 4096 + wave * 1024);   \
  } while (0)

  STAGE(0, kv_begin);
  __syncthreads();
  int buf = 0;

  for (int kv0 = kv_begin; kv0 < kv_end; kv0 += 64) {
    if (kv0 + 64 < kv_end) STAGE(buf ^ 1, kv0 + 64);   // prefetch next tile

    const char* sKb = asmem + buf * 16384;
    const char* sVb = asmem + 32768 + buf * 16384;

    // QK in nf-pairs: 4 independent chains (2 nf x 2 qs), 4-deep each.
#pragma unroll
    for (int nfp = 0; nfp < 2; nfp++) {
      f32x4 s00 = {0.f, 0.f, 0.f, 0.f}, s01 = s00, s10 = s00, s11 = s00;
      __builtin_amdgcn_s_setprio(1);
#pragma unroll
      for (int kk = 0; kk < 4; kk++) {
        int kr0 = (nfp * 2 + 0) * 16 + lr;
        int kr1 = (nfp * 2 + 1) * 16 + lr;
        int db0 = (kk * 64 + lg * 16) ^ ((kr0 & 7) << 4);
        int db1 = (kk * 64 + lg * 16) ^ ((kr1 & 7) << 4);
        bf16x8 kf0 = *(const bf16x8*)(sKb + kr0 * 256 + db0);
        bf16x8 kf1 = *(const bf16x8*)(sKb + kr1 * 256 + db1);
        s00 = mfma16(kf0, qf[0][kk], s00);
        s01 = mfma16(kf0, qf[1][kk], s01);
        s10 = mfma16(kf1, qf[0][kk], s10);
        s11 = mfma16(kf1, qf[1][kk], s11);
      }
      __builtin_amdgcn_s_setprio(0);
      // P = exp2(S); local l accum; write P rows (8B ds_write, swizzled)
      f32x4 scs[2][2] = {{s00, s01}, {s10, s11}};
#pragma unroll
      for (int nfh = 0; nfh < 2; nfh++) {
        int nf = nfp * 2 + nfh;
#pragma unroll
        for (int qs = 0; qs < 2; qs++) {
          float p0 = __builtin_amdgcn_exp2f(scs[nfh][qs][0]);
          float p1 = __builtin_amdgcn_exp2f(scs[nfh][qs][1]);
          float p2 = __builtin_amdgcn_exp2f(scs[nfh][qs][2]);
          float p3 = __builtin_amdgcn_exp2f(scs[nfh][qs][3]);
          lsum[qs] += (p0 + p1) + (p2 + p3);
          bf16x4 pk;
          pk[0] = (bf16)p0; pk[1] = (bf16)p1; pk[2] = (bf16)p2; pk[3] = (bf16)p3;
          *(bf16x4*)(pw + (qs * 16 + lr) * 128 +
                     ((nf * 32 + lg * 8) ^ ((lr & 7) << 4))) = pk;
        }
      }
    }

    // PV: O[32 q][128 d] += P @ V ; vf reads shared across both q-sets
    bf16x8 pa[2][2];
#pragma unroll
    for (int qs = 0; qs < 2; qs++)
#pragma unroll
      for (int kk = 0; kk < 2; kk++) {
        int db = (kk * 64 + lg * 16) ^ ((lr & 7) << 4);
        pa[qs][kk] = *(const bf16x8*)(pw + (qs * 16 + lr) * 128 + db);
      }
    __builtin_amdgcn_s_setprio(1);
#pragma unroll
    for (int df = 0; df < 8; df++) {
#pragma unroll
      for (int kk = 0; kk < 2; kk++) {
        int vrow = df * 16 + lr;
        int db = (kk * 64 + lg * 16) ^ ((vrow & 7) << 4);
        bf16x8 vf = *(const bf16x8*)(sVb + vrow * 128 + db);
        o[0][df] = mfma16(pa[0][kk], vf, o[0][df]);
        o[1][df] = mfma16(pa[1][kk], vf, o[1][df]);
      }
    }
    __builtin_amdgcn_s_setprio(0);
    __syncthreads();   // prefetch landed + LDS sync
    buf ^= 1;
  }
#undef STAGE

  // epilogue: finish l partials, write l + unnormalized bf16 O
#pragma unroll
  for (int qs = 0; qs < 2; qs++) {
    float ls = lsum[qs];
    ls += __shfl_xor(ls, 16);
    ls += __shfl_xor(ls, 32);
    if (lg == 0)
      lbuf[(size_t)(z * 8 + hh) * 4096 + q0 + wave * 32 + qs * 16 + lr] = ls;
#pragma unroll
    for (int df = 0; df < 8; df++) {
      int col = hh * 128 + df * 16 + lr;
#pragma unroll
      for (int r = 0; r < 4; r++) {
        int row = q0 + wave * 32 + qs * 16 + lg * 4 + r;
        obuf[(size_t)row * 1024 + col] = (bf16)o[qs][df][r];
      }
    }
  }
}

// ---------------------------------------------------------------------------
// Launch. Workspace layout (peak 78.5 MB), liveness-ordered reuse (R15):
//   [0,32M)   h/h2/w1T/qkv-tail -> FFN2 partials (liveness-ordered)
//   [32,40M)  vt -> w2T | [40,72M) O partials (2x8MB) -> ffn1
//   [72,72.5M) lbuf | [72.5,78.5M) wTq
// ---------------------------------------------------------------------------
extern "C" void kernel_launch(void* const* d_in, const int* in_sizes, int n_in,
                              void* d_out, int out_size, void* d_ws, size_t ws_size,
                              hipStream_t stream) {
  const float* x     = (const float*)d_in[0];
  const float* ln1_g = (const float*)d_in[1];
  const float* ln1_b = (const float*)d_in[2];
  const float* qkv_w = (const float*)d_in[3];
  const float* qkv_b = (const float*)d_in[4];
  const float* ln2_g = (const float*)d_in[5];
  const float* ln2_b = (const float*)d_in[6];
  const float* w1    = (const float*)d_in[7];
  const float* b1    = (const float*)d_in[8];
  const float* w2    = (const float*)d_in[9];
  const float* b2    = (const float*)d_in[10];

  char* ws = (char*)d_ws;
  const size_t MB = 1ull << 20;
  bf16*  h     = (bf16*)(ws + 0);
  bf16*  qkv   = (bf16*)(ws + 8 * MB);
  bf16*  h2    = (bf16*)(ws + 8 * MB);    // alias: qkv dead after attn
  bf16*  w1T   = (bf16*)(ws + 16 * MB);   // alias: qkv dead after attn
  bf16*  fpart = (bf16*)(ws + 0);         // FFN2 partials z*8MB, [0,32M)
  bf16*  vt    = (bf16*)(ws + 32 * MB);
  bf16*  w2T   = (bf16*)(ws + 32 * MB);   // alias: vt dead after attn
  bf16*  Op    = (bf16*)(ws + 40 * MB);   // 2 x 8MB bf16 partials
  bf16*  ffn1  = (bf16*)(ws + 40 * MB);   // alias: O dead after mid
  float* lbuf  = (float*)(ws + 72 * MB);
  bf16*  wTq   = (bf16*)(ws + 72 * MB + 512 * 1024);
  float* outp  = (float*)d_out;

  // dynamic-LDS caps (idempotent)
  hipFuncSetAttribute(reinterpret_cast<const void*>(gemm8p_kernel<3>),
                      hipFuncAttributeMaxDynamicSharedMemorySize, 131072);
  hipFuncSetAttribute(reinterpret_cast<const void*>(gemm8p_kernel<1>),
                      hipFuncAttributeMaxDynamicSharedMemorySize, 131072);
  hipFuncSetAttribute(reinterpret_cast<const void*>(gemm8p_kernel<4>),
                      hipFuncAttributeMaxDynamicSharedMemorySize, 131072);
  hipFuncSetAttribute(reinterpret_cast<const void*>(attn_kernel),
                      hipFuncAttributeMaxDynamicSharedMemorySize, 81920);

  // 1. LN1 + qkv_w transpose (fused)
  pre_kernel<<<7168, 256, 0, stream>>>(x, ln1_g, ln1_b, h, qkv_w, wTq);
  // 2. qkv = h @ qkv_w + b (Q pre-scaled; V written transposed into vt)
  gemm8p_kernel<3><<<dim3(3072 / 256, 4096 / 256), 512, 131072, stream>>>(
      h, wTq, qkv_b, qkv, vt, 4096, 3072, 1024, 1024);
  // 3. attention, KV-split x2, QBLK=128, dbuf -> bf16 O partials + l
  attn_kernel<<<dim3(32, 8, 2), 256, 81920, stream>>>(qkv, vt, Op, lbuf);
  // 4. w1/w2 transposes + resid_ln2 (fused; qkv/vt regions dead)
  mid_kernel<<<12288, 256, 0, stream>>>(w1, w1T, w2, w2T, Op, lbuf, h,
                                        ln2_g, ln2_b, h2);
  // 5. ffn1 = gelu(h2 @ w1 + b1)  [4096,4096] bf16 (Op region dead)
  gemm8p_kernel<1><<<dim3(4096 / 256, 4096 / 256), 512, 131072, stream>>>(
      h2, w1T, b1, ffn1, nullptr, 4096, 4096, 1024, 1024);
  // 6. FFN2 split-K x4 -> bf16 partials at fpart + z*4096*1024 (ONE launch)
  gemm8p_kernel<4><<<dim3(1024 / 256, 4096 / 256, 4), 512, 131072, stream>>>(
      ffn1, w2T, nullptr, fpart, nullptr, 4096, 1024, 4096, 1024);
  // 7. out = sum_z partial_z + b2  (fp32)
  ffn2_combine_kernel<<<4096, 256, 0, stream>>>(fpart, b2, outp);
}